// Round 2
// baseline (4862.123 us; speedup 1.0000x reference)
//
#include <hip/hip_runtime.h>

// RateRNN: u_{t+1} = clip(u + dt*du), du = (-u + f + r@W^T + bias + eta)*tau_inv
// Persistent kernel, REGULAR launch: 256 WGs x 256 threads (1 WG/CU guaranteed
// resident: <=8KB LDS, <=512 VGPR -> all 256 blocks dispatch immediately; no
// cooperative API needed since we only use flag-based producer/consumer sync).
//   WG g: bt-group bti=g>>6 (16 of 64 sequences), m-slice mi=g&63 (32 of 2048 units).
//   W-slice (32 x 2048) held in REGISTERS as bf16 MFMA B-fragments (128 VGPR/thread).
//   Per step: wait group flags -> load r_t A-fragments from global (double-buffered
//   in d_ws) -> 2x mfma_f32_16x16x32_bf16, K split over 4 waves -> LDS reduce ->
//   pointwise update -> write hist + r_{t+1} + release flag.
// Flag protocol: flags[g] = #r buffers produced. Iteration t waits flags>=t+1
//   (r_t ready AND everyone done reading r_{t-1}, which shares the buffer we
//   write r_{t+1} into), produces r_{t+1}, sets flags=t+2.

#define N_H     2048
#define N_EXC   1638
#define T_STEPS 256
#define BT_TOT  64   // B*TR

typedef __bf16 bf16_t;
typedef __attribute__((ext_vector_type(8))) __bf16 bf16x8;
typedef __attribute__((ext_vector_type(4))) float  f32x4;

__global__ __launch_bounds__(256, 1)
void rnn_persistent(const float* __restrict__ u0,
                    const float* __restrict__ fs,
                    const float* __restrict__ noise,
                    const float* __restrict__ Wrec,
                    const float* __restrict__ bias,
                    float* __restrict__ out,
                    bf16_t* __restrict__ rbuf,   // [2][64][2048] bf16
                    int* __restrict__ flags)     // [256]
{
    const int g    = blockIdx.x;
    const int bti  = g >> 6;          // 0..3
    const int mi   = g & 63;          // 0..63
    const int tid  = threadIdx.x;
    const int wave = tid >> 6;        // 0..3, owns K range [wave*512, +512)
    const int lane = tid & 63;
    const int l15  = lane & 15;
    const int quad = lane >> 4;

    const int bt0 = bti * 16;
    const int m0  = mi * 32;
    const int kw0 = wave * 512;

    float* u_hist  = out;                                   // 64*256*2048
    float* eta_out = out + (size_t)BT_TOT * T_STEPS * N_H;  // 64*2048
    float* du_hist = eta_out + (size_t)BT_TOT * N_H;        // 64*256*2048

    // ---- W-slice into register B-fragments ----
    // B-frag layout (16x16x32): lane holds B[k = quad*8+j][col = lane&15], j=0..7
    // B[k][col] = W[m0 + tile*16 + col][n = kw0 + kk*32 + k]
    bf16x8 Wf[16][2];
#pragma unroll
    for (int kk = 0; kk < 16; ++kk) {
#pragma unroll
      for (int tl = 0; tl < 2; ++tl) {
        const float* wp = Wrec + (size_t)(m0 + tl*16 + l15) * N_H
                               + (kw0 + kk*32 + quad*8);
        bf16x8 v;
#pragma unroll
        for (int j = 0; j < 8; ++j) v[j] = (bf16_t)wp[j];
        Wf[kk][tl] = v;
      }
    }

    // ---- per-thread state: 2 cells (bt = btA+p, n = ncol) ----
    const int nloc = tid & 31;
    const int ncol = m0 + nloc;
    const int btA  = bt0 + (tid >> 5) * 2;
    const float bv   = bias[ncol];
    const float tinv = (ncol < N_EXC) ? 50.0f : 100.0f;  // 1/0.02, 1/0.01

    float u[2];
    u[0] = u0[(size_t)(btA+0) * N_H + ncol];
    u[1] = u0[(size_t)(btA+1) * N_H + ncol];

    // produce r_0 into buffer 0
    rbuf[(size_t)(btA+0)*N_H + ncol] = (bf16_t)fmaxf(u[0], 0.0f);
    rbuf[(size_t)(btA+1)*N_H + ncol] = (bf16_t)fmaxf(u[1], 0.0f);
    __syncthreads();
    if (tid == 0)
      __hip_atomic_store(&flags[g], 1, __ATOMIC_RELEASE, __HIP_MEMORY_SCOPE_AGENT);

    __shared__ float red[4][2][64][4];   // [wave][tile][lane][reg] = 8KB

    const size_t half = (size_t)BT_TOT * N_H;

    for (int t = 0; t < T_STEPS; ++t) {
      // prefetch step-t inputs (independent of r; inputs are never written)
      float fv[2], ev[2];
#pragma unroll
      for (int p = 0; p < 2; ++p) {
        const int bt = btA + p;
        fv[p] = fs[((size_t)bt * T_STEPS + t) * N_H + ncol];
        ev[p] = noise[((size_t)bt * (T_STEPS + 1) + t) * N_H + ncol];
      }

      // wait for the 64 producers of this bt-group: flags >= t+1
      if (wave == 0) {
        const int fi = (bti << 6) | lane;
        int cnt = 0;
        for (;;) {
          int v = __hip_atomic_load(&flags[fi], __ATOMIC_RELAXED,
                                    __HIP_MEMORY_SCOPE_AGENT);
          if (__all(v >= t + 1)) break;
          if (++cnt > (1 << 18)) break;    // safety valve: wrong > hung
          __builtin_amdgcn_s_sleep(2);
        }
        __threadfence();  // acquire: invalidate stale r lines in L1/L2
      }
      __syncthreads();

      // ---- partial GEMM over this wave's K range ----
      // A-frag: lane holds r[bt0 + (lane&15)][kw0 + kk*32 + quad*8 + j]
      const bf16_t* rsrc = rbuf + (size_t)(t & 1) * half;
      const bf16_t* ab = rsrc + (size_t)(bt0 + l15) * N_H + (kw0 + quad * 8);
      f32x4 acc0 = {0.f,0.f,0.f,0.f}, acc1 = {0.f,0.f,0.f,0.f};
#pragma unroll
      for (int kk = 0; kk < 16; ++kk) {
        bf16x8 a = *(const bf16x8*)(ab + kk * 32);
        acc0 = __builtin_amdgcn_mfma_f32_16x16x32_bf16(a, Wf[kk][0], acc0, 0, 0, 0);
        acc1 = __builtin_amdgcn_mfma_f32_16x16x32_bf16(a, Wf[kk][1], acc1, 0, 0, 0);
      }

      // ---- cross-wave K reduction via LDS ----
      *reinterpret_cast<f32x4*>(&red[wave][0][lane][0]) = acc0;
      *reinterpret_cast<f32x4*>(&red[wave][1][lane][0]) = acc1;
      __syncthreads();

      // C/D layout: col = lane&15 (= m within tile), row = quad*4 + reg (= bt)
      const int tile = nloc >> 4;
      const int col  = nloc & 15;
      bf16_t* rdst = rbuf + (size_t)((t + 1) & 1) * half;
#pragma unroll
      for (int p = 0; p < 2; ++p) {
        const int bt   = btA + p;
        const int row  = bt - bt0;                 // 0..15
        const int srcl = (row >> 2) * 16 + col;
        const int reg  = row & 3;
        float rec = red[0][tile][srcl][reg] + red[1][tile][srcl][reg]
                  + red[2][tile][srcl][reg] + red[3][tile][srcl][reg];
        float du = (-u[p] + fv[p] + rec + bv + ev[p]) * tinv;
        float un = u[p] + du * 0.001f;
        un = fminf(fmaxf(un, -5.0f), 5.0f);
        u[p] = un;
        const size_t o = ((size_t)bt * T_STEPS + t) * N_H + ncol;
        u_hist[o]  = un;
        du_hist[o] = du;
        rdst[(size_t)bt * N_H + ncol] = (bf16_t)fmaxf(un, 0.0f);
      }
      __syncthreads();   // all rbuf stores drained (barrier waits vmcnt)
      if (tid == 0)
        __hip_atomic_store(&flags[g], t + 2, __ATOMIC_RELEASE,
                           __HIP_MEMORY_SCOPE_AGENT);
    }

    // eta_final = noise[:, :, T]
#pragma unroll
    for (int p = 0; p < 2; ++p) {
      const int bt = btA + p;
      eta_out[(size_t)bt * N_H + ncol] =
          noise[((size_t)bt * (T_STEPS + 1) + T_STEPS) * N_H + ncol];
    }
}

extern "C" void kernel_launch(void* const* d_in, const int* in_sizes, int n_in,
                              void* d_out, int out_size, void* d_ws, size_t ws_size,
                              hipStream_t stream) {
    const float* u0    = (const float*)d_in[0];
    const float* fs    = (const float*)d_in[1];
    const float* noise = (const float*)d_in[2];
    const float* Wrec  = (const float*)d_in[3];
    const float* bias  = (const float*)d_in[4];
    float* out = (float*)d_out;

    // d_ws layout: [0,4096) flags (256 ints used), [4096, +512KB) r double buffer
    int*    flags = (int*)d_ws;
    bf16_t* rbuf  = (bf16_t*)((char*)d_ws + 4096);

    hipMemsetAsync(d_ws, 0, 4096, stream);   // flags must start at 0 every call

    rnn_persistent<<<dim3(256), dim3(256), 0, stream>>>(
        u0, fs, noise, Wrec, bias, out, rbuf, flags);
}